// Round 9
// baseline (414.830 us; speedup 1.0000x reference)
//
#include <hip/hip_runtime.h>
#include <math.h>

#define NN 50000
#define NE 800000
#define NB 196        // dst buckets of 256 nodes: (NN+255)>>8

typedef float v4f __attribute__((ext_vector_type(4)));
typedef short v8s __attribute__((ext_vector_type(8)));

__device__ __forceinline__ unsigned short f2bf(float f) {
  unsigned u = __float_as_uint(f);
  u = u + 0x7FFFu + ((u >> 16) & 1u);
  return (unsigned short)(u >> 16);
}
__device__ __forceinline__ float bf2f(unsigned short h) {
  return __uint_as_float(((unsigned)h) << 16);
}

// ================= graph build: two-level bucket sort (dense writes) ==========

__global__ __launch_bounds__(256) void k_bhist(const int* __restrict__ dst,
                                               int* __restrict__ gbcnt) {
  __shared__ int lcnt[NB];
  int t = threadIdx.x;
  for (int i = t; i < NB; i += 256) lcnt[i] = 0;
  __syncthreads();
  int eb = blockIdx.x * 4096;
#pragma unroll
  for (int i = 0; i < 16; ++i) {
    int e = eb + i * 256 + t;
    if (e < NE) atomicAdd(&lcnt[dst[e] >> 8], 1);
  }
  __syncthreads();
  for (int i = t; i < NB; i += 256)
    if (lcnt[i]) atomicAdd(&gbcnt[i], lcnt[i]);
}

__global__ __launch_bounds__(256) void k_bscan(const int* __restrict__ gbcnt,
                                               int* __restrict__ boff,
                                               int* __restrict__ gcur,
                                               int* __restrict__ offs) {
  __shared__ int sd[256];
  int t = threadIdx.x;
  int v = (t < NB) ? gbcnt[t] : 0;
  sd[t] = v;
  __syncthreads();
  for (int o = 1; o < 256; o <<= 1) {
    int u = (t >= o) ? sd[t - o] : 0;
    __syncthreads();
    sd[t] += u;
    __syncthreads();
  }
  if (t < NB) { int x = sd[t] - v; boff[t] = x; gcur[t] = x; }
  if (t == NB - 1) boff[NB] = sd[t];
  if (t == 0) offs[NN] = NE;
}

__global__ __launch_bounds__(256) void k_bscatter(const int* __restrict__ src,
                                                  const int* __restrict__ dst,
                                                  int* __restrict__ gcur,
                                                  unsigned* __restrict__ ebuf) {
  __shared__ int cnt[NB];
  __shared__ int base[NB];
  int t = threadIdx.x;
  for (int i = t; i < NB; i += 256) cnt[i] = 0;
  __syncthreads();
  int eb = blockIdx.x * 4096;
  unsigned pk[16];
  int bk[16], lp[16];
#pragma unroll
  for (int i = 0; i < 16; ++i) {
    int e = eb + i * 256 + t;
    if (e < NE) {
      int d = dst[e];
      int b = d >> 8;
      pk[i] = ((unsigned)src[e] << 8) | (unsigned)(d & 255);
      bk[i] = b;
      lp[i] = atomicAdd(&cnt[b], 1);
    }
  }
  __syncthreads();
  for (int i = t; i < NB; i += 256)
    base[i] = cnt[i] ? atomicAdd(&gcur[i], cnt[i]) : 0;
  __syncthreads();
#pragma unroll
  for (int i = 0; i < 16; ++i) {
    int e = eb + i * 256 + t;
    if (e < NE) ebuf[base[bk[i]] + lp[i]] = pk[i];
  }
}

__global__ __launch_bounds__(256) void k_bbuild(const unsigned* __restrict__ ebuf,
                                                const int* __restrict__ boff,
                                                int* __restrict__ offs,
                                                float* __restrict__ invd,
                                                int* __restrict__ csr) {
  __shared__ int dcnt[256];
  __shared__ int cur[256];
  int t = threadIdx.x;
  int b = blockIdx.x;
  int node0 = b << 8;
  int es = boff[b], ee = boff[b + 1];
  dcnt[t] = 0;
  __syncthreads();
  for (int e = es + t; e < ee; e += 256) atomicAdd(&dcnt[ebuf[e] & 255], 1);
  __syncthreads();
  int v = dcnt[t];
  cur[t] = v;
  __syncthreads();
  for (int o = 1; o < 256; o <<= 1) {
    int u = (t >= o) ? cur[t - o] : 0;
    __syncthreads();
    cur[t] += u;
    __syncthreads();
  }
  int excl = cur[t] - v;
  int node = node0 + t;
  if (node < NN) {
    offs[node] = es + excl;
    invd[node] = 1.0f / fmaxf((float)v, 1.0f);
  }
  __syncthreads();
  cur[t] = es + excl;
  __syncthreads();
  for (int e = es + t; e < ee; e += 256) {
    unsigned pk = ebuf[e];
    int p = atomicAdd(&cur[pk & 255], 1);
    csr[p] = (int)(pk >> 8);
  }
}

// ================= per-node mean aggregation (interleaved hi|lo rows) =========
__global__ __launch_bounds__(256) void k_aggregate(
    const unsigned short* __restrict__ feat,
    const int* __restrict__ offs, const int* __restrict__ csr,
    const float* __restrict__ invd,
    unsigned short* __restrict__ mean, int n) {
  int node = blockIdx.x * 4 + (threadIdx.x >> 6);
  int lane = threadIdx.x & 63;
  int nsub = lane >> 4;     // 0..3 neighbor slot
  int cg   = lane & 15;     // 16 groups x 8 ushort = full 256B row
  if (node >= n) return;
  int s = offs[node], e = offs[node + 1];

  float a[8];
#pragma unroll
  for (int i = 0; i < 8; ++i) a[i] = 0.f;

  if (e > s) {
    int emax = e - 1;
    for (int p0 = s; p0 < e; p0 += 16) {
      int pa = p0 + nsub, pb = p0 + 4 + nsub, pc = p0 + 8 + nsub, pd = p0 + 12 + nsub;
      int ja = csr[pa < emax ? pa : emax];
      int jb = csr[pb < emax ? pb : emax];
      int jc = csr[pc < emax ? pc : emax];
      int jd = csr[pd < emax ? pd : emax];
      v8s va = *(const v8s*)(feat + (size_t)ja * 128 + cg * 8);
      v8s vb = *(const v8s*)(feat + (size_t)jb * 128 + cg * 8);
      v8s vc = *(const v8s*)(feat + (size_t)jc * 128 + cg * 8);
      v8s vd = *(const v8s*)(feat + (size_t)jd * 128 + cg * 8);
      if (pa < e) {
#pragma unroll
        for (int i = 0; i < 8; ++i) a[i] += bf2f((unsigned short)va[i]);
      }
      if (pb < e) {
#pragma unroll
        for (int i = 0; i < 8; ++i) a[i] += bf2f((unsigned short)vb[i]);
      }
      if (pc < e) {
#pragma unroll
        for (int i = 0; i < 8; ++i) a[i] += bf2f((unsigned short)vc[i]);
      }
      if (pd < e) {
#pragma unroll
        for (int i = 0; i < 8; ++i) a[i] += bf2f((unsigned short)vd[i]);
      }
    }
  }
#pragma unroll
  for (int i = 0; i < 8; ++i) {
    a[i] += __shfl_xor(a[i], 8, 64);   // hi + lo plane
    a[i] += __shfl_xor(a[i], 16, 64);  // neighbor slots
    a[i] += __shfl_xor(a[i], 32, 64);
  }
  if (lane < 8) {
    float d = invd[node];
    v8s oh, ol;
#pragma unroll
    for (int i = 0; i < 8; ++i) {
      float m = a[i] * d;
      unsigned short h = f2bf(m);
      oh[i] = (short)h;
      ol[i] = (short)f2bf(m - bf2f(h));
    }
    *(v8s*)(mean + (size_t)node * 128 + lane * 8) = oh;
    *(v8s*)(mean + (size_t)node * 128 + 64 + lane * 8) = ol;
  }
}

// ================= fused multi-source linear, MFMA split-bf16 =================
// Software-pipelined: iteration s issues loadA(s+1)+loadW(s+1) (global),
// computes s from registers (no wait), then stages s+1 (waitcnt lands here),
// one barrier per source. A-latency hidden under the MFMA/LDS stream.
struct LinArgs {
  const void*  a[6];       // fp32 ptr (isf32) or bf16 interleaved-row ptr
  const float* w[6];       // [64][64] fp32 blocks (row stride 64)
  int gidx[6];
  int stride[6];           // fp32 row stride
  int isf32[6];
  int nsrc;
  const float* bias;
  const float* skip;
  unsigned short* outp;    // [n][128] interleaved hi|lo
  float* colsum;           // [64] atomic target, or nullptr
  int n;
  int relu;
};

__global__ __launch_bounds__(256) void k_linear(LinArgs A) {
  __shared__ unsigned short sW[2][2][64 * 72];   // [buf][hi/lo][n*72+k]
  const int t    = threadIdx.x;
  const int lane = t & 63;
  const int wv   = t >> 6;
  const int qd   = lane >> 4;
  const int ln   = lane & 15;
  const int n0   = blockIdx.x * 64;

  v4f acc[4];
#pragma unroll
  for (int ct = 0; ct < 4; ++ct) acc[ct] = (v4f){0.f, 0.f, 0.f, 0.f};

  const int sn = t & 63;
  float wreg[16];
  auto loadW = [&](int s) {
    const float* w = A.w[s];
#pragma unroll
    for (int c = 0; c < 2; ++c) {
      int kb = (wv + 4 * c) * 8;
#pragma unroll
      for (int j = 0; j < 8; ++j)
        wreg[c * 8 + j] = w[(size_t)(kb + j) * 64 + sn];
    }
  };
  auto writeW = [&](int s, int b) {
    float gs = 1.0f;
    if (A.gidx[s] >= 0) gs = 1.0f / (1.0f + __expf(-A.skip[A.gidx[s]]));
#pragma unroll
    for (int c = 0; c < 2; ++c) {
      int cb = wv + 4 * c;
      v8s hv, lv;
#pragma unroll
      for (int j = 0; j < 8; ++j) {
        float f = wreg[c * 8 + j] * gs;
        unsigned short h = f2bf(f);
        hv[j] = (short)h;
        lv[j] = (short)f2bf(f - bf2f(h));
      }
      *(v8s*)(&sW[b][0][sn * 72 + cb * 8]) = hv;
      *(v8s*)(&sW[b][1][sn * 72 + cb * 8]) = lv;
    }
  };

  const int arow = n0 + wv * 16 + ln;
  const bool arv = arow < A.n;

  // A pipeline registers: raw (just-loaded) and cur (staged, compute-ready)
  v8s rawh[2], rawl[2];     // bf16 path raw loads
  float rawf[16];           // fp32 path raw loads
  v8s curh[2], curl[2];
  auto loadA = [&](int s) {
    if (A.isf32[s]) {
      const float* a = (const float*)A.a[s];
      int st = A.stride[s];
      if (arv) {
#pragma unroll
        for (int ks = 0; ks < 2; ++ks) {
          const float* p = a + (size_t)arow * st + ks * 32 + qd * 8;
          float4 u0 = *(const float4*)(p);
          float4 u1 = *(const float4*)(p + 4);
          rawf[ks * 8 + 0] = u0.x; rawf[ks * 8 + 1] = u0.y;
          rawf[ks * 8 + 2] = u0.z; rawf[ks * 8 + 3] = u0.w;
          rawf[ks * 8 + 4] = u1.x; rawf[ks * 8 + 5] = u1.y;
          rawf[ks * 8 + 6] = u1.z; rawf[ks * 8 + 7] = u1.w;
        }
      } else {
#pragma unroll
        for (int j = 0; j < 16; ++j) rawf[j] = 0.f;
      }
    } else {
      const unsigned short* ph = (const unsigned short*)A.a[s] + (size_t)arow * 128;
      if (arv) {
#pragma unroll
        for (int ks = 0; ks < 2; ++ks) {
          rawh[ks] = *(const v8s*)(ph + ks * 32 + qd * 8);
          rawl[ks] = *(const v8s*)(ph + 64 + ks * 32 + qd * 8);
        }
      } else {
        v8s z;
#pragma unroll
        for (int j = 0; j < 8; ++j) z[j] = 0;
        rawh[0] = rawh[1] = rawl[0] = rawl[1] = z;
      }
    }
  };
  // stage raw -> cur (fp32 path: split-convert here, AFTER compute, so the
  // load waitcnt doesn't stall the MFMA stream)
  auto stageA = [&](int s) {
    if (A.isf32[s]) {
#pragma unroll
      for (int ks = 0; ks < 2; ++ks) {
        v8s hv, lv;
#pragma unroll
        for (int j = 0; j < 8; ++j) {
          float f = rawf[ks * 8 + j];
          unsigned short h = f2bf(f);
          hv[j] = (short)h;
          lv[j] = (short)f2bf(f - bf2f(h));
        }
        curh[ks] = hv; curl[ks] = lv;
      }
    } else {
#pragma unroll
      for (int ks = 0; ks < 2; ++ks) { curh[ks] = rawh[ks]; curl[ks] = rawl[ks]; }
    }
  };

  // prologue: source 0 fully staged
  loadW(0);
  loadA(0);
  writeW(0, 0);
  stageA(0);
  __syncthreads();

  for (int s = 0; s < A.nsrc; ++s) {
    if (s + 1 < A.nsrc) {
      loadA(s + 1);       // issue globals early; results not consumed yet
      loadW(s + 1);
    }
    const unsigned short* wh = &sW[s & 1][0][0];
    const unsigned short* wl = &sW[s & 1][1][0];
#pragma unroll
    for (int ks = 0; ks < 2; ++ks) {
#pragma unroll
      for (int ct = 0; ct < 4; ++ct) {
        int wn = ct * 16 + ln;
        v8s bh = *(const v8s*)(wh + wn * 72 + ks * 32 + qd * 8);
        v8s bl = *(const v8s*)(wl + wn * 72 + ks * 32 + qd * 8);
        acc[ct] = __builtin_amdgcn_mfma_f32_16x16x32_bf16(curh[ks], bh, acc[ct], 0, 0, 0);
        acc[ct] = __builtin_amdgcn_mfma_f32_16x16x32_bf16(curl[ks], bh, acc[ct], 0, 0, 0);
        acc[ct] = __builtin_amdgcn_mfma_f32_16x16x32_bf16(curh[ks], bl, acc[ct], 0, 0, 0);
      }
    }
    if (s + 1 < A.nsrc) {
      writeW(s + 1, (s + 1) & 1);   // waitcnt for prefetches lands here
      stageA(s + 1);
    }
    __syncthreads();
  }

  float bvals[4];
#pragma unroll
  for (int ct = 0; ct < 4; ++ct) bvals[ct] = A.bias[ct * 16 + ln];

  float cs[4] = {0.f, 0.f, 0.f, 0.f};
#pragma unroll
  for (int ct = 0; ct < 4; ++ct) {
#pragma unroll
    for (int r = 0; r < 4; ++r) {
      int node = n0 + wv * 16 + qd * 4 + r;   // C/D: row=(lane>>4)*4+reg, col=lane&15
      float v = acc[ct][r] + bvals[ct];
      if (A.relu) v = fmaxf(v, 0.f);
      if (node < A.n) {
        unsigned short h = f2bf(v);
        A.outp[(size_t)node * 128 + ct * 16 + ln] = h;
        A.outp[(size_t)node * 128 + 64 + ct * 16 + ln] = f2bf(v - bf2f(h));
        cs[ct] += v;
      }
    }
  }
  if (A.colsum) {
    float* red = (float*)&sW[0][0][0];
#pragma unroll
    for (int ct = 0; ct < 4; ++ct) {
      float v = cs[ct];
      v += __shfl_xor(v, 16, 64);
      v += __shfl_xor(v, 32, 64);
      if (qd == 0) red[wv * 64 + ct * 16 + ln] = v;
    }
    __syncthreads();
    if (t < 64) {
      float ssum = red[t] + red[64 + t] + red[128 + t] + red[192 + t];
      atomicAdd(&A.colsum[t], ssum);
    }
  }
}

// ---------------- tiny post-MLP (single block) ----------------
__global__ __launch_bounds__(256) void k_post(const float* __restrict__ s,
                                              const float* __restrict__ w1, const float* __restrict__ b1,
                                              const float* __restrict__ w2, const float* __restrict__ b2,
                                              const float* __restrict__ w3, const float* __restrict__ b3,
                                              const float* __restrict__ w4, const float* __restrict__ b4,
                                              float* __restrict__ outp) {
  __shared__ float sh[256], h1[64], h2[64], h3[256];
  int t = threadIdx.x;
  sh[t] = s[t];
  __syncthreads();
  if (t < 64) {
    float a = b1[t];
    for (int k = 0; k < 256; ++k) a += sh[k] * w1[k * 64 + t];
    h1[t] = (a >= 0.f) ? a : 0.1f * a;   // leaky_relu 0.1
  }
  __syncthreads();
  if (t < 64) {
    float a = b2[t];
    for (int k = 0; k < 64; ++k) a += h1[k] * w2[k * 64 + t];
    h2[t] = fmaxf(a, 0.f);
  }
  __syncthreads();
  {
    float a = b3[t];
    for (int k = 0; k < 64; ++k) a += h2[k] * w3[k * 256 + t];
    h3[t] = fmaxf(a, 0.f);
  }
  __syncthreads();
  if (t < 64) {
    float a = b4[t];
    for (int k = 0; k < 256; ++k) a += h3[k] * w4[k * 64 + t];
    outp[t] = a;
  }
}

extern "C" void kernel_launch(void* const* d_in, const int* in_sizes, int n_in,
                              void* d_out, int out_size, void* d_ws, size_t ws_size,
                              hipStream_t stream) {
  const float* nf     = (const float*)d_in[0];
  const int*   ei     = (const int*)d_in[1];
  const float* pre_w1 = (const float*)d_in[2];
  const float* pre_b1 = (const float*)d_in[3];
  const float* pre_w2 = (const float*)d_in[4];
  const float* pre_b2 = (const float*)d_in[5];
  const float* skip   = (const float*)d_in[6];
  const float* wl0 = (const float*)d_in[7],  *bl0 = (const float*)d_in[8],  *wr0 = (const float*)d_in[9];
  const float* wl1 = (const float*)d_in[10], *bl1 = (const float*)d_in[11], *wr1 = (const float*)d_in[12];
  const float* wl2 = (const float*)d_in[13], *bl2 = (const float*)d_in[14], *wr2 = (const float*)d_in[15];
  const float* pw1 = (const float*)d_in[16], *pb1 = (const float*)d_in[17];
  const float* pw2 = (const float*)d_in[18], *pb2 = (const float*)d_in[19];
  const float* pw3 = (const float*)d_in[20], *pb3 = (const float*)d_in[21];
  const float* pw4 = (const float*)d_in[22], *pb4 = (const float*)d_in[23];
  float* out = (float*)d_out;

  const int N = NN, E = NE;

  // workspace carve-up
  char* ws = (char*)d_ws;
  size_t pos = 0;
  auto alloc = [&](size_t bytes) {
    char* p = ws + pos;
    pos += (bytes + 255) & ~(size_t)255;
    return (void*)p;
  };
  int*      gbcnt = (int*)alloc((size_t)NB * 4);
  int*      boff  = (int*)alloc((size_t)(NB + 1) * 4);
  int*      gcur  = (int*)alloc((size_t)NB * 4);
  unsigned* ebuf  = (unsigned*)alloc((size_t)E * 4);
  int*      offs  = (int*)alloc((size_t)(N + 1) * 4);
  float*    invd  = (float*)alloc((size_t)N * 4);
  int*      csr   = (int*)alloc((size_t)E * 4);
  const size_t PB = (size_t)N * 128 * 2;   // interleaved hi|lo rows, bytes
  unsigned short* x  = (unsigned short*)alloc(PB);
  unsigned short* h0 = (unsigned short*)alloc(PB);
  unsigned short* h1 = (unsigned short*)alloc(PB);
  unsigned short* h2 = (unsigned short*)alloc(PB);
  unsigned short* m0 = (unsigned short*)alloc(PB);
  unsigned short* m1 = (unsigned short*)alloc(PB);
  unsigned short* m2 = (unsigned short*)alloc(PB);
  unsigned short* t0 = m2;            // pre-MLP hidden; dead before m2 is written
  float* sv = (float*)alloc(256 * 4);

  hipMemsetAsync(gbcnt, 0, (size_t)NB * 4, stream);
  hipMemsetAsync(sv, 0, 256 * 4, stream);

  const int* e_src = ei;
  const int* e_dst = ei + E;
  const int EGRID = (E + 4095) / 4096;   // 196
  k_bhist<<<EGRID, 256, 0, stream>>>(e_dst, gbcnt);
  k_bscan<<<1, 256, 0, stream>>>(gbcnt, boff, gcur, offs);
  k_bscatter<<<EGRID, 256, 0, stream>>>(e_src, e_dst, gcur, ebuf);
  k_bbuild<<<NB, 256, 0, stream>>>(ebuf, boff, offs, invd, csr);

  const int LGRID = (N + 63) / 64;   // 782
  auto lin = [&](int nsrc,
                 const void* a0, int f0, int s0, const float* w0, int g0,
                 const void* a1, int f1, int s1, const float* w1_, int g1,
                 const void* a2, int f2, int s2, const float* w2_, int g2,
                 const void* a3, int f3, int s3, const float* w3_, int g3,
                 const void* a4, int f4, int s4, const float* w4_, int g4,
                 const void* a5, int f5, int s5, const float* w5_, int g5,
                 const float* bias, unsigned short* op, float* colsum, int relu) {
    LinArgs A;
    A.a[0] = a0; A.a[1] = a1; A.a[2] = a2; A.a[3] = a3; A.a[4] = a4; A.a[5] = a5;
    A.w[0] = w0; A.w[1] = w1_; A.w[2] = w2_; A.w[3] = w3_; A.w[4] = w4_; A.w[5] = w5_;
    A.gidx[0] = g0; A.gidx[1] = g1; A.gidx[2] = g2; A.gidx[3] = g3; A.gidx[4] = g4; A.gidx[5] = g5;
    A.stride[0] = s0; A.stride[1] = s1; A.stride[2] = s2; A.stride[3] = s3; A.stride[4] = s4; A.stride[5] = s5;
    A.isf32[0] = f0; A.isf32[1] = f1; A.isf32[2] = f2; A.isf32[3] = f3; A.isf32[4] = f4; A.isf32[5] = f5;
    A.nsrc = nsrc; A.bias = bias; A.skip = skip;
    A.outp = op; A.colsum = colsum;
    A.n = N; A.relu = relu;
    k_linear<<<LGRID, 256, 0, stream>>>(A);
  };

  // pre_mlp pass1: t0 = relu(nf @ pre_w1 + pre_b1)  (K=128 -> 2 fp32 sources)
  lin(2, nf, 1, 128, pre_w1, -1, nf + 64, 1, 128, pre_w1 + 64 * 64, -1,
      nullptr, 0, 0, nullptr, -1, nullptr, 0, 0, nullptr, -1,
      nullptr, 0, 0, nullptr, -1, nullptr, 0, 0, nullptr, -1,
      pre_b1, t0, nullptr, 1);
  // pre_mlp pass2: x = t0 @ pre_w2 + pre_b2  (fused colsum -> sv[0:64])
  lin(1, t0, 0, 0, pre_w2, -1,
      nullptr, 0, 0, nullptr, -1, nullptr, 0, 0, nullptr, -1,
      nullptr, 0, 0, nullptr, -1, nullptr, 0, 0, nullptr, -1,
      nullptr, 0, 0, nullptr, -1, pre_b2, x, sv, 0);

  // layer 0
  k_aggregate<<<(N + 3) / 4, 256, 0, stream>>>(x, offs, csr, invd, m0, N);
  lin(2, m0, 0, 0, wl0, 0, x, 0, 0, wr0, 0,
      nullptr, 0, 0, nullptr, -1, nullptr, 0, 0, nullptr, -1,
      nullptr, 0, 0, nullptr, -1, nullptr, 0, 0, nullptr, -1,
      bl0, h0, sv + 64, 1);

  // layer 1 (gates skip[1][0]=idx3, skip[1][1]=idx4)
  k_aggregate<<<(N + 3) / 4, 256, 0, stream>>>(h0, offs, csr, invd, m1, N);
  lin(4, m0, 0, 0, wl1, 3, m1, 0, 0, wl1 + 64 * 64, 4,
      x, 0, 0, wr1, 3, h0, 0, 0, wr1 + 64 * 64, 4,
      nullptr, 0, 0, nullptr, -1, nullptr, 0, 0, nullptr, -1,
      bl1, h1, sv + 128, 1);

  // layer 2 (gates skip[2][0..2] = idx 6,7,8)
  k_aggregate<<<(N + 3) / 4, 256, 0, stream>>>(h1, offs, csr, invd, m2, N);
  lin(6, m0, 0, 0, wl2, 6, m1, 0, 0, wl2 + 64 * 64, 7, m2, 0, 0, wl2 + 128 * 64, 8,
      x, 0, 0, wr2, 6, h0, 0, 0, wr2 + 64 * 64, 7, h1, 0, 0, wr2 + 128 * 64, 8,
      bl2, h2, sv + 192, 1);

  // post-MLP on the fused column sums
  k_post<<<1, 256, 0, stream>>>(sv, pw1, pb1, pw2, pb2, pw3, pb3, pw4, pb4, out);
}

// Round 10
// 407.720 us; speedup vs baseline: 1.0174x; 1.0174x over previous
//
#include <hip/hip_runtime.h>
#include <math.h>

#define NN 50000
#define NE 800000
#define NB 196        // dst buckets of 256 nodes: (NN+255)>>8

typedef float v4f __attribute__((ext_vector_type(4)));
typedef short v8s __attribute__((ext_vector_type(8)));

__device__ __forceinline__ unsigned short f2bf(float f) {
  unsigned u = __float_as_uint(f);
  u = u + 0x7FFFu + ((u >> 16) & 1u);
  return (unsigned short)(u >> 16);
}
__device__ __forceinline__ float bf2f(unsigned short h) {
  return __uint_as_float(((unsigned)h) << 16);
}

// ================= graph build: two-level bucket sort (dense writes) ==========

__global__ __launch_bounds__(256) void k_bhist(const int* __restrict__ dst,
                                               int* __restrict__ gbcnt) {
  __shared__ int lcnt[NB];
  int t = threadIdx.x;
  for (int i = t; i < NB; i += 256) lcnt[i] = 0;
  __syncthreads();
  int eb = blockIdx.x * 4096;
#pragma unroll
  for (int i = 0; i < 16; ++i) {
    int e = eb + i * 256 + t;
    if (e < NE) atomicAdd(&lcnt[dst[e] >> 8], 1);
  }
  __syncthreads();
  for (int i = t; i < NB; i += 256)
    if (lcnt[i]) atomicAdd(&gbcnt[i], lcnt[i]);
}

__global__ __launch_bounds__(256) void k_bscan(const int* __restrict__ gbcnt,
                                               int* __restrict__ boff,
                                               int* __restrict__ gcur,
                                               int* __restrict__ offs) {
  __shared__ int sd[256];
  int t = threadIdx.x;
  int v = (t < NB) ? gbcnt[t] : 0;
  sd[t] = v;
  __syncthreads();
  for (int o = 1; o < 256; o <<= 1) {
    int u = (t >= o) ? sd[t - o] : 0;
    __syncthreads();
    sd[t] += u;
    __syncthreads();
  }
  if (t < NB) { int x = sd[t] - v; boff[t] = x; gcur[t] = x; }
  if (t == NB - 1) boff[NB] = sd[t];
  if (t == 0) offs[NN] = NE;
}

__global__ __launch_bounds__(256) void k_bscatter(const int* __restrict__ src,
                                                  const int* __restrict__ dst,
                                                  int* __restrict__ gcur,
                                                  unsigned* __restrict__ ebuf) {
  __shared__ int cnt[NB];
  __shared__ int base[NB];
  int t = threadIdx.x;
  for (int i = t; i < NB; i += 256) cnt[i] = 0;
  __syncthreads();
  int eb = blockIdx.x * 4096;
  unsigned pk[16];
  int bk[16], lp[16];
#pragma unroll
  for (int i = 0; i < 16; ++i) {
    int e = eb + i * 256 + t;
    if (e < NE) {
      int d = dst[e];
      int b = d >> 8;
      pk[i] = ((unsigned)src[e] << 8) | (unsigned)(d & 255);
      bk[i] = b;
      lp[i] = atomicAdd(&cnt[b], 1);
    }
  }
  __syncthreads();
  for (int i = t; i < NB; i += 256)
    base[i] = cnt[i] ? atomicAdd(&gcur[i], cnt[i]) : 0;
  __syncthreads();
#pragma unroll
  for (int i = 0; i < 16; ++i) {
    int e = eb + i * 256 + t;
    if (e < NE) ebuf[base[bk[i]] + lp[i]] = pk[i];
  }
}

__global__ __launch_bounds__(256) void k_bbuild(const unsigned* __restrict__ ebuf,
                                                const int* __restrict__ boff,
                                                int* __restrict__ offs,
                                                float* __restrict__ invd,
                                                int* __restrict__ csr) {
  __shared__ int dcnt[256];
  __shared__ int cur[256];
  int t = threadIdx.x;
  int b = blockIdx.x;
  int node0 = b << 8;
  int es = boff[b], ee = boff[b + 1];
  dcnt[t] = 0;
  __syncthreads();
  for (int e = es + t; e < ee; e += 256) atomicAdd(&dcnt[ebuf[e] & 255], 1);
  __syncthreads();
  int v = dcnt[t];
  cur[t] = v;
  __syncthreads();
  for (int o = 1; o < 256; o <<= 1) {
    int u = (t >= o) ? cur[t - o] : 0;
    __syncthreads();
    cur[t] += u;
    __syncthreads();
  }
  int excl = cur[t] - v;
  int node = node0 + t;
  if (node < NN) {
    offs[node] = es + excl;
    invd[node] = 1.0f / fmaxf((float)v, 1.0f);
  }
  __syncthreads();
  cur[t] = es + excl;
  __syncthreads();
  for (int e = es + t; e < ee; e += 256) {
    unsigned pk = ebuf[e];
    int p = atomicAdd(&cur[pk & 255], 1);
    csr[p] = (int)(pk >> 8);
  }
}

// ================= per-node mean aggregation (interleaved hi|lo rows) =========
__global__ __launch_bounds__(256) void k_aggregate(
    const unsigned short* __restrict__ feat,
    const int* __restrict__ offs, const int* __restrict__ csr,
    const float* __restrict__ invd,
    unsigned short* __restrict__ mean, int n) {
  int node = blockIdx.x * 4 + (threadIdx.x >> 6);
  int lane = threadIdx.x & 63;
  int nsub = lane >> 4;     // 0..3 neighbor slot
  int cg   = lane & 15;     // 16 groups x 8 ushort = full 256B row
  if (node >= n) return;
  int s = offs[node], e = offs[node + 1];

  float a[8];
#pragma unroll
  for (int i = 0; i < 8; ++i) a[i] = 0.f;

  if (e > s) {
    int emax = e - 1;
    for (int p0 = s; p0 < e; p0 += 16) {
      int pa = p0 + nsub, pb = p0 + 4 + nsub, pc = p0 + 8 + nsub, pd = p0 + 12 + nsub;
      int ja = csr[pa < emax ? pa : emax];
      int jb = csr[pb < emax ? pb : emax];
      int jc = csr[pc < emax ? pc : emax];
      int jd = csr[pd < emax ? pd : emax];
      v8s va = *(const v8s*)(feat + (size_t)ja * 128 + cg * 8);
      v8s vb = *(const v8s*)(feat + (size_t)jb * 128 + cg * 8);
      v8s vc = *(const v8s*)(feat + (size_t)jc * 128 + cg * 8);
      v8s vd = *(const v8s*)(feat + (size_t)jd * 128 + cg * 8);
      if (pa < e) {
#pragma unroll
        for (int i = 0; i < 8; ++i) a[i] += bf2f((unsigned short)va[i]);
      }
      if (pb < e) {
#pragma unroll
        for (int i = 0; i < 8; ++i) a[i] += bf2f((unsigned short)vb[i]);
      }
      if (pc < e) {
#pragma unroll
        for (int i = 0; i < 8; ++i) a[i] += bf2f((unsigned short)vc[i]);
      }
      if (pd < e) {
#pragma unroll
        for (int i = 0; i < 8; ++i) a[i] += bf2f((unsigned short)vd[i]);
      }
    }
  }
#pragma unroll
  for (int i = 0; i < 8; ++i) {
    a[i] += __shfl_xor(a[i], 8, 64);   // hi + lo plane
    a[i] += __shfl_xor(a[i], 16, 64);  // neighbor slots
    a[i] += __shfl_xor(a[i], 32, 64);
  }
  if (lane < 8) {
    float d = invd[node];
    v8s oh, ol;
#pragma unroll
    for (int i = 0; i < 8; ++i) {
      float m = a[i] * d;
      unsigned short h = f2bf(m);
      oh[i] = (short)h;
      ol[i] = (short)f2bf(m - bf2f(h));
    }
    *(v8s*)(mean + (size_t)node * 128 + lane * 8) = oh;
    *(v8s*)(mean + (size_t)node * 128 + 64 + lane * 8) = ol;
  }
}

// ================= W pre-pack: fragment-ready bf16 hi/lo, gates folded =======
// 15 slots, each a 64x64 fp32 W-block -> per plane 4096 ushorts laid out as
// ((ks*4+ct)*64 + lane)*8 + j  with value W[ks*32+(lane>>4)*8+j][ct*16+(lane&15)].
// slot data: hi at slot*8192, lo at slot*8192+4096.
struct WPrepArgs {
  const float* w[15];   // block base (row offset pre-applied), row stride 64
  int gidx[15];         // skip index or -1
  const float* skip;
  unsigned short* wbuf;
};

__global__ __launch_bounds__(256) void k_wprep(WPrepArgs P) {
  int slot = blockIdx.x;
  int t = threadIdx.x;
  const float* w = P.w[slot];
  float gs = 1.0f;
  if (P.gidx[slot] >= 0) gs = 1.0f / (1.0f + __expf(-P.skip[P.gidx[slot]]));
  unsigned short* hi = P.wbuf + (size_t)slot * 8192;
  unsigned short* lo = hi + 4096;
#pragma unroll
  for (int half = 0; half < 2; ++half) {
    int p = t + 256 * half;          // 0..511
    int frag = p >> 6, lane = p & 63;
    int ks = frag >> 2, ct = frag & 3;
    int qd = lane >> 4, ln = lane & 15;
    v8s hv, lv;
#pragma unroll
    for (int j = 0; j < 8; ++j) {
      float f = w[(size_t)(ks * 32 + qd * 8 + j) * 64 + ct * 16 + ln] * gs;
      unsigned short h = f2bf(f);
      hv[j] = (short)h;
      lv[j] = (short)f2bf(f - bf2f(h));
    }
    *(v8s*)(hi + (size_t)p * 8) = hv;
    *(v8s*)(lo + (size_t)p * 8) = lv;
  }
}

// ================= fused multi-source linear: barrier-free MFMA ==============
// out = act( sum_s A_s @ (g_s W_s) + bias ).  W comes fragment-ready from wbuf
// (gates pre-folded) -> NO LDS staging, NO __syncthreads in the K-loop.
// A(s+1) prefetches into registers during compute(s); with no barrier the
// vmcnt wait lands after the MFMA stream and TLP covers L2-hot B loads.
struct LinArgs {
  const void* a[6];        // fp32 ptr (isf32) or bf16 interleaved-row ptr
  int isf32[6];
  int stride[6];           // fp32 row stride
  int slot0;               // first W slot; sources use slot0, slot0+1, ...
  int nsrc;
  const float* bias;
  const unsigned short* wbuf;
  unsigned short* outp;    // [n][128] interleaved hi|lo
  float* colsum;           // [64] atomic target, or nullptr
  int n;
  int relu;
};

__global__ __launch_bounds__(256) void k_linear(LinArgs A) {
  __shared__ float red[256];
  const int t    = threadIdx.x;
  const int lane = t & 63;
  const int wv   = t >> 6;
  const int qd   = lane >> 4;
  const int ln   = lane & 15;
  const int n0   = blockIdx.x * 64;

  v4f acc[4];
#pragma unroll
  for (int ct = 0; ct < 4; ++ct) acc[ct] = (v4f){0.f, 0.f, 0.f, 0.f};

  const int arow = n0 + wv * 16 + ln;
  const bool arv = arow < A.n;

  v8s rawh[2], rawl[2];
  float rawf[16];
  v8s curh[2], curl[2];
  auto loadA = [&](int s) {
    if (A.isf32[s]) {
      const float* a = (const float*)A.a[s];
      int st = A.stride[s];
      if (arv) {
#pragma unroll
        for (int ks = 0; ks < 2; ++ks) {
          const float* p = a + (size_t)arow * st + ks * 32 + qd * 8;
          float4 u0 = *(const float4*)(p);
          float4 u1 = *(const float4*)(p + 4);
          rawf[ks * 8 + 0] = u0.x; rawf[ks * 8 + 1] = u0.y;
          rawf[ks * 8 + 2] = u0.z; rawf[ks * 8 + 3] = u0.w;
          rawf[ks * 8 + 4] = u1.x; rawf[ks * 8 + 5] = u1.y;
          rawf[ks * 8 + 6] = u1.z; rawf[ks * 8 + 7] = u1.w;
        }
      } else {
#pragma unroll
        for (int j = 0; j < 16; ++j) rawf[j] = 0.f;
      }
    } else {
      const unsigned short* ph = (const unsigned short*)A.a[s] + (size_t)arow * 128;
      if (arv) {
#pragma unroll
        for (int ks = 0; ks < 2; ++ks) {
          rawh[ks] = *(const v8s*)(ph + ks * 32 + qd * 8);
          rawl[ks] = *(const v8s*)(ph + 64 + ks * 32 + qd * 8);
        }
      } else {
        v8s z;
#pragma unroll
        for (int j = 0; j < 8; ++j) z[j] = 0;
        rawh[0] = rawh[1] = rawl[0] = rawl[1] = z;
      }
    }
  };
  auto stageA = [&](int s) {
    if (A.isf32[s]) {
#pragma unroll
      for (int ks = 0; ks < 2; ++ks) {
        v8s hv, lv;
#pragma unroll
        for (int j = 0; j < 8; ++j) {
          float f = rawf[ks * 8 + j];
          unsigned short h = f2bf(f);
          hv[j] = (short)h;
          lv[j] = (short)f2bf(f - bf2f(h));
        }
        curh[ks] = hv; curl[ks] = lv;
      }
    } else {
#pragma unroll
      for (int ks = 0; ks < 2; ++ks) { curh[ks] = rawh[ks]; curl[ks] = rawl[ks]; }
    }
  };

  loadA(0);
  stageA(0);

  for (int s = 0; s < A.nsrc; ++s) {
    if (s + 1 < A.nsrc) loadA(s + 1);   // prefetch; no barrier -> truly hidden
    const unsigned short* wb = A.wbuf + (size_t)(A.slot0 + s) * 8192;
#pragma unroll
    for (int ks = 0; ks < 2; ++ks) {
#pragma unroll
      for (int ct = 0; ct < 4; ++ct) {
        const unsigned short* fp = wb + (size_t)((ks * 4 + ct) * 64 + lane) * 8;
        v8s bh = *(const v8s*)(fp);
        v8s bl = *(const v8s*)(fp + 4096);
        acc[ct] = __builtin_amdgcn_mfma_f32_16x16x32_bf16(curh[ks], bh, acc[ct], 0, 0, 0);
        acc[ct] = __builtin_amdgcn_mfma_f32_16x16x32_bf16(curl[ks], bh, acc[ct], 0, 0, 0);
        acc[ct] = __builtin_amdgcn_mfma_f32_16x16x32_bf16(curh[ks], bl, acc[ct], 0, 0, 0);
      }
    }
    if (s + 1 < A.nsrc) stageA(s + 1);
  }

  float bvals[4];
#pragma unroll
  for (int ct = 0; ct < 4; ++ct) bvals[ct] = A.bias[ct * 16 + ln];

  float cs[4] = {0.f, 0.f, 0.f, 0.f};
#pragma unroll
  for (int ct = 0; ct < 4; ++ct) {
#pragma unroll
    for (int r = 0; r < 4; ++r) {
      int node = n0 + wv * 16 + qd * 4 + r;   // C/D: row=(lane>>4)*4+reg, col=lane&15
      float v = acc[ct][r] + bvals[ct];
      if (A.relu) v = fmaxf(v, 0.f);
      if (node < A.n) {
        unsigned short h = f2bf(v);
        A.outp[(size_t)node * 128 + ct * 16 + ln] = h;
        A.outp[(size_t)node * 128 + 64 + ct * 16 + ln] = f2bf(v - bf2f(h));
        cs[ct] += v;
      }
    }
  }
  if (A.colsum) {
#pragma unroll
    for (int ct = 0; ct < 4; ++ct) {
      float v = cs[ct];
      v += __shfl_xor(v, 16, 64);
      v += __shfl_xor(v, 32, 64);
      if (qd == 0) red[wv * 64 + ct * 16 + ln] = v;
    }
    __syncthreads();
    if (t < 64) {
      float ssum = red[t] + red[64 + t] + red[128 + t] + red[192 + t];
      atomicAdd(&A.colsum[t], ssum);
    }
  }
}

// ---------------- tiny post-MLP (single block) ----------------
__global__ __launch_bounds__(256) void k_post(const float* __restrict__ s,
                                              const float* __restrict__ w1, const float* __restrict__ b1,
                                              const float* __restrict__ w2, const float* __restrict__ b2,
                                              const float* __restrict__ w3, const float* __restrict__ b3,
                                              const float* __restrict__ w4, const float* __restrict__ b4,
                                              float* __restrict__ outp) {
  __shared__ float sh[256], h1[64], h2[64], h3[256];
  int t = threadIdx.x;
  sh[t] = s[t];
  __syncthreads();
  if (t < 64) {
    float a = b1[t];
    for (int k = 0; k < 256; ++k) a += sh[k] * w1[k * 64 + t];
    h1[t] = (a >= 0.f) ? a : 0.1f * a;   // leaky_relu 0.1
  }
  __syncthreads();
  if (t < 64) {
    float a = b2[t];
    for (int k = 0; k < 64; ++k) a += h1[k] * w2[k * 64 + t];
    h2[t] = fmaxf(a, 0.f);
  }
  __syncthreads();
  {
    float a = b3[t];
    for (int k = 0; k < 64; ++k) a += h2[k] * w3[k * 256 + t];
    h3[t] = fmaxf(a, 0.f);
  }
  __syncthreads();
  if (t < 64) {
    float a = b4[t];
    for (int k = 0; k < 256; ++k) a += h3[k] * w4[k * 64 + t];
    outp[t] = a;
  }
}

extern "C" void kernel_launch(void* const* d_in, const int* in_sizes, int n_in,
                              void* d_out, int out_size, void* d_ws, size_t ws_size,
                              hipStream_t stream) {
  const float* nf     = (const float*)d_in[0];
  const int*   ei     = (const int*)d_in[1];
  const float* pre_w1 = (const float*)d_in[2];
  const float* pre_b1 = (const float*)d_in[3];
  const float* pre_w2 = (const float*)d_in[4];
  const float* pre_b2 = (const float*)d_in[5];
  const float* skip   = (const float*)d_in[6];
  const float* wl0 = (const float*)d_in[7],  *bl0 = (const float*)d_in[8],  *wr0 = (const float*)d_in[9];
  const float* wl1 = (const float*)d_in[10], *bl1 = (const float*)d_in[11], *wr1 = (const float*)d_in[12];
  const float* wl2 = (const float*)d_in[13], *bl2 = (const float*)d_in[14], *wr2 = (const float*)d_in[15];
  const float* pw1 = (const float*)d_in[16], *pb1 = (const float*)d_in[17];
  const float* pw2 = (const float*)d_in[18], *pb2 = (const float*)d_in[19];
  const float* pw3 = (const float*)d_in[20], *pb3 = (const float*)d_in[21];
  const float* pw4 = (const float*)d_in[22], *pb4 = (const float*)d_in[23];
  float* out = (float*)d_out;

  const int N = NN, E = NE;

  // workspace carve-up
  char* ws = (char*)d_ws;
  size_t pos = 0;
  auto alloc = [&](size_t bytes) {
    char* p = ws + pos;
    pos += (bytes + 255) & ~(size_t)255;
    return (void*)p;
  };
  int*      gbcnt = (int*)alloc((size_t)NB * 4);
  int*      boff  = (int*)alloc((size_t)(NB + 1) * 4);
  int*      gcur  = (int*)alloc((size_t)NB * 4);
  unsigned* ebuf  = (unsigned*)alloc((size_t)E * 4);
  int*      offs  = (int*)alloc((size_t)(N + 1) * 4);
  float*    invd  = (float*)alloc((size_t)N * 4);
  int*      csr   = (int*)alloc((size_t)E * 4);
  unsigned short* wbuf = (unsigned short*)alloc((size_t)15 * 8192 * 2);
  const size_t PB = (size_t)N * 128 * 2;   // interleaved hi|lo rows, bytes
  unsigned short* x  = (unsigned short*)alloc(PB);
  unsigned short* h0 = (unsigned short*)alloc(PB);
  unsigned short* h1 = (unsigned short*)alloc(PB);
  unsigned short* h2 = (unsigned short*)alloc(PB);
  unsigned short* m0 = (unsigned short*)alloc(PB);
  unsigned short* m1 = (unsigned short*)alloc(PB);
  unsigned short* m2 = (unsigned short*)alloc(PB);
  unsigned short* t0 = m2;            // pre-MLP hidden; dead before m2 is written
  float* sv = (float*)alloc(256 * 4);

  hipMemsetAsync(gbcnt, 0, (size_t)NB * 4, stream);
  hipMemsetAsync(sv, 0, 256 * 4, stream);

  // ---- W pre-pack: slots 0..14 ----
  {
    WPrepArgs P;
    const float* wsrc[15] = {
      pre_w1, pre_w1 + 64 * 64,            // 0,1  pre pass1
      pre_w2,                              // 2    pre pass2
      wl0, wr0,                            // 3,4  layer0
      wl1, wl1 + 64 * 64, wr1, wr1 + 64 * 64,            // 5-8 layer1
      wl2, wl2 + 64 * 64, wl2 + 128 * 64,                // 9-11 layer2 L
      wr2, wr2 + 64 * 64, wr2 + 128 * 64                 // 12-14 layer2 R
    };
    int gi[15] = {-1, -1, -1, 0, 0, 3, 4, 3, 4, 6, 7, 8, 6, 7, 8};
    for (int i = 0; i < 15; ++i) { P.w[i] = wsrc[i]; P.gidx[i] = gi[i]; }
    P.skip = skip; P.wbuf = wbuf;
    k_wprep<<<15, 256, 0, stream>>>(P);
  }

  const int* e_src = ei;
  const int* e_dst = ei + E;
  const int EGRID = (E + 4095) / 4096;   // 196
  k_bhist<<<EGRID, 256, 0, stream>>>(e_dst, gbcnt);
  k_bscan<<<1, 256, 0, stream>>>(gbcnt, boff, gcur, offs);
  k_bscatter<<<EGRID, 256, 0, stream>>>(e_src, e_dst, gcur, ebuf);
  k_bbuild<<<NB, 256, 0, stream>>>(ebuf, boff, offs, invd, csr);

  const int LGRID = (N + 63) / 64;   // 782
  auto lin = [&](int nsrc, int slot0,
                 const void* a0, int f0, int s0,
                 const void* a1, int f1, int s1,
                 const void* a2, int f2, int s2,
                 const void* a3, int f3, int s3,
                 const void* a4, int f4, int s4,
                 const void* a5, int f5, int s5,
                 const float* bias, unsigned short* op, float* colsum, int relu) {
    LinArgs A;
    A.a[0] = a0; A.a[1] = a1; A.a[2] = a2; A.a[3] = a3; A.a[4] = a4; A.a[5] = a5;
    A.isf32[0] = f0; A.isf32[1] = f1; A.isf32[2] = f2; A.isf32[3] = f3; A.isf32[4] = f4; A.isf32[5] = f5;
    A.stride[0] = s0; A.stride[1] = s1; A.stride[2] = s2; A.stride[3] = s3; A.stride[4] = s4; A.stride[5] = s5;
    A.slot0 = slot0; A.nsrc = nsrc; A.bias = bias; A.wbuf = wbuf;
    A.outp = op; A.colsum = colsum;
    A.n = N; A.relu = relu;
    k_linear<<<LGRID, 256, 0, stream>>>(A);
  };

  // pre_mlp pass1: t0 = relu(nf @ pre_w1 + pre_b1)  (slots 0,1)
  lin(2, 0, nf, 1, 128, nf + 64, 1, 128,
      nullptr, 0, 0, nullptr, 0, 0, nullptr, 0, 0, nullptr, 0, 0,
      pre_b1, t0, nullptr, 1);
  // pre_mlp pass2: x = t0 @ pre_w2 + pre_b2  (slot 2; fused colsum -> sv[0:64])
  lin(1, 2, t0, 0, 0,
      nullptr, 0, 0, nullptr, 0, 0, nullptr, 0, 0, nullptr, 0, 0, nullptr, 0, 0,
      pre_b2, x, sv, 0);

  // layer 0 (slots 3,4)
  k_aggregate<<<(N + 3) / 4, 256, 0, stream>>>(x, offs, csr, invd, m0, N);
  lin(2, 3, m0, 0, 0, x, 0, 0,
      nullptr, 0, 0, nullptr, 0, 0, nullptr, 0, 0, nullptr, 0, 0,
      bl0, h0, sv + 64, 1);

  // layer 1 (slots 5-8)
  k_aggregate<<<(N + 3) / 4, 256, 0, stream>>>(h0, offs, csr, invd, m1, N);
  lin(4, 5, m0, 0, 0, m1, 0, 0, x, 0, 0, h0, 0, 0,
      nullptr, 0, 0, nullptr, 0, 0,
      bl1, h1, sv + 128, 1);

  // layer 2 (slots 9-14)
  k_aggregate<<<(N + 3) / 4, 256, 0, stream>>>(h1, offs, csr, invd, m2, N);
  lin(6, 9, m0, 0, 0, m1, 0, 0, m2, 0, 0, x, 0, 0, h0, 0, 0, h1, 0, 0,
      bl2, h2, sv + 192, 1);

  // post-MLP on the fused column sums
  k_post<<<1, 256, 0, stream>>>(sv, pw1, pb1, pw2, pb2, pw3, pb3, pw4, pb4, out);
}